// Round 1
// baseline (9905.074 us; speedup 1.0000x reference)
//
#include <hip/hip_runtime.h>
#include <cstdint>
#include <cstddef>

#define NN 50000
#define EE 1600000
#define GG 512
#define FIN 1273

__device__ __forceinline__ float sigmf(float x) { return 1.f / (1.f + expf(-x)); }

// ---------------- fp32 tiled GEMM: C[M,Nc] = A[M,K] * B + (bias) ----------------
// BT=false: B is [K,Nc] row-major.  BT=true: B is [Nc,K] row-major (B transposed).
// Tile 64x128, block 256 threads, K-chunk 32. Optional fused per-column sum/sumsq
// (only used when Nc==128, single column tile).
template <bool BT>
__global__ __launch_bounds__(256) void gemm_f32(
    const float* __restrict__ A, const float* __restrict__ B,
    const float* __restrict__ bias, float* __restrict__ C,
    int M, int K, int Nc, int do_stats, float* __restrict__ stats)
{
    __shared__ float As[32][68];   // [kk][row], 16B-aligned rows
    __shared__ float Bs[32][132];  // [kk][col]
    __shared__ float ssum[128], ssq[128];
    const int tid = threadIdx.x;
    const int tx = tid & 15, ty = tid >> 4;
    const int row0 = blockIdx.x * 64, col0 = blockIdx.y * 128;
    float acc[4][8] = {};

    for (int k0 = 0; k0 < K; k0 += 32) {
        {   // A tile: 64x32 -> As[kk][r]
            const int kk = tid & 31, rb = tid >> 5;
            #pragma unroll
            for (int i = 0; i < 8; ++i) {
                const int r = rb + i * 8, gr = row0 + r, gk = k0 + kk;
                As[kk][r] = (gr < M && gk < K) ? A[(size_t)gr * K + gk] : 0.f;
            }
        }
        if (!BT) {
            const int c = tid & 127, kb = tid >> 7;
            #pragma unroll
            for (int i = 0; i < 16; ++i) {
                const int kk = kb + i * 2, gk = k0 + kk;
                Bs[kk][c] = (gk < K) ? B[(size_t)gk * Nc + col0 + c] : 0.f;
            }
        } else {
            const int kk = tid & 31, cb = tid >> 5;
            #pragma unroll
            for (int i = 0; i < 16; ++i) {
                const int c = cb + i * 8, gk = k0 + kk;
                Bs[kk][c] = (gk < K) ? B[(size_t)(col0 + c) * K + gk] : 0.f;
            }
        }
        __syncthreads();
        #pragma unroll 8
        for (int kk = 0; kk < 32; ++kk) {
            const float4 av  = *(const float4*)&As[kk][ty * 4];
            const float4 bv0 = *(const float4*)&Bs[kk][tx * 8];
            const float4 bv1 = *(const float4*)&Bs[kk][tx * 8 + 4];
            const float a[4] = {av.x, av.y, av.z, av.w};
            const float b[8] = {bv0.x, bv0.y, bv0.z, bv0.w, bv1.x, bv1.y, bv1.z, bv1.w};
            #pragma unroll
            for (int i = 0; i < 4; ++i)
                #pragma unroll
                for (int j = 0; j < 8; ++j)
                    acc[i][j] = fmaf(a[i], b[j], acc[i][j]);
        }
        __syncthreads();
    }

    #pragma unroll
    for (int j = 0; j < 8; ++j) {
        const float bv = bias ? bias[col0 + tx * 8 + j] : 0.f;
        #pragma unroll
        for (int i = 0; i < 4; ++i) acc[i][j] += bv;
    }
    #pragma unroll
    for (int i = 0; i < 4; ++i) {
        const int gr = row0 + ty * 4 + i;
        if (gr < M) {
            *(float4*)&C[(size_t)gr * Nc + col0 + tx * 8] =
                make_float4(acc[i][0], acc[i][1], acc[i][2], acc[i][3]);
            *(float4*)&C[(size_t)gr * Nc + col0 + tx * 8 + 4] =
                make_float4(acc[i][4], acc[i][5], acc[i][6], acc[i][7]);
        }
    }
    if (do_stats) {  // per-column sum / sumsq (Nc==128, col0==0)
        if (tid < 128) { ssum[tid] = 0.f; ssq[tid] = 0.f; }
        __syncthreads();
        #pragma unroll
        for (int j = 0; j < 8; ++j) {
            float s = 0.f, q = 0.f;
            #pragma unroll
            for (int i = 0; i < 4; ++i) {
                const int gr = row0 + ty * 4 + i;
                if (gr < M) { const float v = acc[i][j]; s += v; q += v * v; }
            }
            atomicAdd(&ssum[tx * 8 + j], s);
            atomicAdd(&ssq[tx * 8 + j], q);
        }
        __syncthreads();
        if (tid < 128) {
            atomicAdd(&stats[tid],       ssum[tid]);
            atomicAdd(&stats[128 + tid], ssq[tid]);
        }
    }
}

// ---------------- CSR build (counting sort by destination) ----------------
__global__ __launch_bounds__(256) void count_deg(const int* __restrict__ dst,
                                                 int* __restrict__ deg) {
    const int e = blockIdx.x * 256 + threadIdx.x;
    if (e < EE) atomicAdd(&deg[dst[e]], 1);
}

__global__ __launch_bounds__(512) void scan1(const int* __restrict__ deg,
                                             int* __restrict__ scanned,
                                             int* __restrict__ bsum) {
    __shared__ int s[512];
    const int t = threadIdx.x;
    const int i = blockIdx.x * 512 + t;
    const int v = (i < NN) ? deg[i] : 0;
    s[t] = v; __syncthreads();
    for (int o = 1; o < 512; o <<= 1) {
        const int tv = (t >= o) ? s[t - o] : 0;
        __syncthreads();
        s[t] += tv;
        __syncthreads();
    }
    if (i < NN) scanned[i] = s[t];
    if (t == 511) bsum[blockIdx.x] = s[511];
}

__global__ __launch_bounds__(128) void scan2(int* __restrict__ bsum, int nb) {
    __shared__ int s[128];
    const int t = threadIdx.x;
    const int v = (t < nb) ? bsum[t] : 0;
    s[t] = v; __syncthreads();
    for (int o = 1; o < 128; o <<= 1) {
        const int tv = (t >= o) ? s[t - o] : 0;
        __syncthreads();
        s[t] += tv;
        __syncthreads();
    }
    if (t < nb) bsum[t] = s[t] - v;  // exclusive
}

__global__ __launch_bounds__(256) void scan3(const int* __restrict__ deg,
                                             const int* __restrict__ scanned,
                                             const int* __restrict__ bsum,
                                             int* __restrict__ rowptr,
                                             int* __restrict__ cursor) {
    const int i = blockIdx.x * 256 + threadIdx.x;
    if (i < NN) {
        const int v = bsum[i >> 9] + scanned[i] - deg[i];
        rowptr[i] = v; cursor[i] = v;
    }
    if (i == 0) rowptr[NN] = EE;   // total degree == E
}

__global__ __launch_bounds__(256) void fill_csr(const int* __restrict__ src,
                                                const int* __restrict__ dst,
                                                int* __restrict__ cursor,
                                                int* __restrict__ csrc) {
    const int e = blockIdx.x * 256 + threadIdx.x;
    if (e < EE) {
        const int pos = atomicAdd(&cursor[dst[e]], 1);
        csrc[pos] = src[e];
    }
}

// ---------------- neighbor aggregation: one wave per destination node ----------
__global__ __launch_bounds__(256) void aggregate(const float* __restrict__ proj,
                                                 const int* __restrict__ rowptr,
                                                 const int* __restrict__ csrc,
                                                 float* __restrict__ agg) {
    const int wid = (int)((blockIdx.x * 256 + threadIdx.x) >> 6);
    const int lane = threadIdx.x & 63;
    if (wid >= NN) return;
    const int s0 = rowptr[wid], s1 = rowptr[wid + 1];
    const float2* p2 = (const float2*)proj;
    float ax = 0.f, ay = 0.f;
    int j = s0;
    for (; j + 3 < s1; j += 4) {
        const int i0 = csrc[j], i1 = csrc[j + 1], i2 = csrc[j + 2], i3 = csrc[j + 3];
        const float2 v0 = p2[(size_t)i0 * 64 + lane];
        const float2 v1 = p2[(size_t)i1 * 64 + lane];
        const float2 v2 = p2[(size_t)i2 * 64 + lane];
        const float2 v3 = p2[(size_t)i3 * 64 + lane];
        ax += v0.x + v1.x + v2.x + v3.x;
        ay += v0.y + v1.y + v2.y + v3.y;
    }
    for (; j < s1; ++j) {
        const float2 v = p2[(size_t)csrc[j] * 64 + lane];
        ax += v.x; ay += v.y;
    }
    float2 r; r.x = ax; r.y = ay;
    ((float2*)agg)[(size_t)wid * 64 + lane] = r;
}

// ------------- z = (1+eps)*proj + agg + b1 (in-place into proj) + BN stats ------
__global__ __launch_bounds__(256) void combine_z_stats(
    float* __restrict__ z, const float* __restrict__ agg,
    const float* __restrict__ b1, const float* __restrict__ eps_arr, int eps_idx,
    float* __restrict__ stats)
{
    const float e1 = 1.f + eps_arr[eps_idx];
    const int gt = blockIdx.x * 256 + threadIdx.x;
    const int d = gt & 127;
    const float bv = b1[d];
    const size_t stride = 1024 * 256;   // grid fixed at 1024 blocks; multiple of 128
    float s = 0.f, q = 0.f;
    for (size_t i = gt; i < (size_t)NN * 128; i += stride) {
        const float v = fmaf(e1, z[i], agg[i] + bv);
        z[i] = v; s += v; q += v * v;
    }
    atomicAdd(&stats[d], s);
    atomicAdd(&stats[128 + d], q);
}

// ---------------- BN (training-mode batch stats) + ReLU, strided output --------
__global__ __launch_bounds__(256) void bn_relu(
    const float* __restrict__ xin, const float* __restrict__ stats,
    const float* __restrict__ gamma, const float* __restrict__ beta,
    float* __restrict__ out, int ostride, int ooff)
{
    const size_t i = (size_t)blockIdx.x * 256 + threadIdx.x;
    if (i >= (size_t)NN * 128) return;
    const int d = (int)(i & 127);
    const size_t n = i >> 7;
    const float mu  = stats[d] * (1.f / NN);
    const float var = fmaxf(stats[128 + d] * (1.f / NN) - mu * mu, 0.f);
    const float inv = rsqrtf(var + 1e-5f);
    const float v = fmaf(gamma[d] * inv, xin[i] - mu, beta[d]);
    out[n * (size_t)ostride + ooff + d] = fmaxf(v, 0.f);
}

// ---------------- per-graph segment starts (batch is sorted) -------------------
__global__ __launch_bounds__(256) void seg_starts(const int* __restrict__ batch,
                                                  int* __restrict__ gstart) {
    const int i = blockIdx.x * 256 + threadIdx.x;
    if (i >= NN) return;
    const int b = batch[i];
    if (i == 0) { for (int g = 0; g <= b; ++g) gstart[g] = 0; }
    else {
        const int pb = batch[i - 1];
        for (int g = pb + 1; g <= b; ++g) gstart[g] = i;
    }
    if (i == NN - 1) { for (int g = b + 1; g <= GG; ++g) gstart[g] = NN; }
}

// ---------------- Set2Set helpers ----------------------------------------------
__global__ __launch_bounds__(256) void pack_wcat(const float* __restrict__ Wih,
                                                 const float* __restrict__ Whh,
                                                 float* __restrict__ Wcat) {
    const int i = blockIdx.x * 256 + threadIdx.x;
    if (i >= 512 * 384) return;
    const int j = i / 384, k = i - j * 384;
    Wcat[i] = (k < 256) ? Wih[j * 256 + k] : Whh[j * 128 + (k - 256)];
}

__global__ __launch_bounds__(256) void lstm_kernel(
    const float* __restrict__ gates, const float* __restrict__ bih,
    const float* __restrict__ bhh, float* __restrict__ cc, float* __restrict__ S)
{
    const int i = blockIdx.x * 256 + threadIdx.x;
    if (i >= GG * 128) return;
    const int g = i >> 7, d = i & 127;
    const float* gr = gates + (size_t)g * 512;
    const float ig = gr[d]       + bih[d]       + bhh[d];
    const float fg = gr[128 + d] + bih[128 + d] + bhh[128 + d];
    const float gv = gr[256 + d] + bih[256 + d] + bhh[256 + d];
    const float og = gr[384 + d] + bih[384 + d] + bhh[384 + d];
    const float c  = sigmf(fg) * cc[i] + sigmf(ig) * tanhf(gv);
    const float hv = sigmf(og) * tanhf(c);
    cc[i] = c;
    S[(size_t)g * 384 + d] = hv;         // q part of q_star
    S[(size_t)g * 384 + 256 + d] = hv;   // hh (LSTM state / attention query)
}

// per-graph attention: e=h·q, softmax over segment, r = sum a*h -> S[:,128:256]
__global__ __launch_bounds__(256) void attend_kernel(
    const float* __restrict__ h, float* __restrict__ S,
    float* __restrict__ ews, const int* __restrict__ gstart)
{
    const int g = blockIdx.x;
    const int rs = gstart[g], re = gstart[g + 1];
    const int tid = threadIdx.x, lane = tid & 63, w = tid >> 6;
    __shared__ float q[128];
    __shared__ float red[8];
    if (tid < 128) q[tid] = S[(size_t)g * 384 + 256 + tid];
    __syncthreads();
    float lmax = -1e30f;
    for (int n = rs + w; n < re; n += 4) {
        const float* hr = h + (size_t)n * 128;
        float p = hr[lane] * q[lane] + hr[lane + 64] * q[lane + 64];
        #pragma unroll
        for (int o = 32; o; o >>= 1) p += __shfl_down(p, o, 64);
        if (lane == 0) { ews[n] = p; lmax = fmaxf(lmax, p); }
    }
    if (lane == 0) red[w] = lmax;
    __syncthreads();
    const float m = fmaxf(fmaxf(red[0], red[1]), fmaxf(red[2], red[3]));
    __syncthreads();
    float lsum = 0.f;
    for (int n = rs + tid; n < re; n += 256) {
        const float ex = expf(ews[n] - m);
        ews[n] = ex; lsum += ex;
    }
    #pragma unroll
    for (int o = 32; o; o >>= 1) lsum += __shfl_down(lsum, o, 64);
    if (lane == 0) red[w] = lsum;
    __syncthreads();
    const float denom = red[0] + red[1] + red[2] + red[3];
    if (tid < 128) {
        float acc = 0.f;
        for (int n = rs; n < re; ++n)
            acc = fmaf(ews[n], h[(size_t)n * 128 + tid], acc);
        S[(size_t)g * 384 + 128 + tid] = (denom > 0.f) ? acc / denom : 0.f;
    }
}

__global__ __launch_bounds__(128) void fc1_kernel(const float* __restrict__ S,
                                                  const float* __restrict__ W,
                                                  const float* __restrict__ b,
                                                  float* __restrict__ out1) {
    const int g = blockIdx.x, d = threadIdx.x;
    __shared__ float qs[256];
    qs[d] = S[(size_t)g * 384 + d];
    qs[128 + d] = S[(size_t)g * 384 + 128 + d];
    __syncthreads();
    float acc = b[d];
    for (int k = 0; k < 256; ++k) acc = fmaf(qs[k], W[k * 128 + d], acc);
    out1[(size_t)g * 128 + d] = fmaxf(acc, 0.f);
}

__global__ __launch_bounds__(256) void fc4_kernel(const float* __restrict__ out1,
                                                  const float* __restrict__ W,
                                                  const float* __restrict__ b,
                                                  float* __restrict__ out) {
    const int i = blockIdx.x * 256 + threadIdx.x;
    if (i >= GG * 12) return;
    const int g = i / 12, j = i - g * 12;
    float acc = b[j];
    for (int d = 0; d < 128; ++d)
        acc = fmaf(out1[(size_t)g * 128 + d], W[d * 12 + j], acc);
    out[i] = acc;
}

// ================================================================================
extern "C" void kernel_launch(void* const* d_in, const int* in_sizes, int n_in,
                              void* d_out, int out_size, void* d_ws, size_t ws_size,
                              hipStream_t stream)
{
    const float* x        = (const float*)d_in[0];
    const int*   eidx[3]  = {(const int*)d_in[1], (const int*)d_in[2], (const int*)d_in[3]};
    const int*   batch    = (const int*)d_in[4];
    const float* conv1_W1     = (const float*)d_in[5];
    const float* conv1_b1     = (const float*)d_in[6];
    const float* conv_rest_W1 = (const float*)d_in[7];
    const float* conv_rest_b1 = (const float*)d_in[8];
    const float* conv_W2      = (const float*)d_in[9];
    const float* conv_b2      = (const float*)d_in[10];
    const float* conv_bn1_g   = (const float*)d_in[11];
    const float* conv_bn1_b   = (const float*)d_in[12];
    const float* conv_bn2_g   = (const float*)d_in[13];
    const float* conv_bn2_b   = (const float*)d_in[14];
    const float* conv_eps     = (const float*)d_in[15];
    const float* mlp_W1       = (const float*)d_in[16];
    const float* mlp_b1       = (const float*)d_in[17];
    const float* mlp_bn1_g    = (const float*)d_in[18];
    const float* mlp_bn1_b    = (const float*)d_in[19];
    const float* mlp_W2       = (const float*)d_in[20];
    const float* mlp_b2       = (const float*)d_in[21];
    const float* mlp_bn2_g    = (const float*)d_in[22];
    const float* mlp_bn2_b    = (const float*)d_in[23];
    const float* lstm_Wih     = (const float*)d_in[24];
    const float* lstm_Whh     = (const float*)d_in[25];
    const float* lstm_bih     = (const float*)d_in[26];
    const float* lstm_bhh     = (const float*)d_in[27];
    const float* fc1_W        = (const float*)d_in[28];
    const float* fc1_b        = (const float*)d_in[29];
    const float* fc4_W        = (const float*)d_in[30];
    const float* fc4_b        = (const float*)d_in[31];
    float* outp = (float*)d_out;

    // ---- workspace layout (bump allocator) ----
    float* f = (float*)d_ws;
    size_t fo = 0;
    float* h     = f + fo; fo += (size_t)NN * 128;
    float* t1    = f + fo; fo += (size_t)NN * 128;
    float* t2    = f + fo; fo += (size_t)NN * 128;
    float* xcat  = f + fo; fo += (size_t)NN * 384;
    float* ews   = f + fo; fo += NN;
    float* stats = f + fo; fo += 48 * 256;
    float* S     = f + fo; fo += (size_t)GG * 384;
    float* ccb   = f + fo; fo += (size_t)GG * 128;
    float* gates = f + fo; fo += (size_t)GG * 512;  // reused as fc1 output
    float* Wcat  = f + fo; fo += (size_t)512 * 384;
    int* ip = (int*)(f + fo);
    size_t io = 0;
    int* rowptr[3]; int* csrc[3];
    for (int s = 0; s < 3; ++s) { rowptr[s] = ip + io; io += NN + 1; }
    for (int s = 0; s < 3; ++s) { csrc[s]   = ip + io; io += EE; }
    int* deg     = ip + io; io += NN;
    int* cursor  = ip + io; io += NN;
    int* scanned = ip + io; io += NN;
    int* bsum    = ip + io; io += 128;
    int* gstart  = ip + io; io += GG + 1;
    const size_t need = fo * sizeof(float) + io * sizeof(int);
    if (ws_size < need) return;  // workspace too small — fail loudly via validation

    const int NBLK_SCAN = (NN + 511) / 512;  // 98

    // ---- CSR build for the 3 edge sets ----
    for (int s = 0; s < 3; ++s) {
        hipMemsetAsync(deg, 0, NN * sizeof(int), stream);
        count_deg<<<(EE + 255) / 256, 256, 0, stream>>>(eidx[s] + EE, deg);
        scan1<<<NBLK_SCAN, 512, 0, stream>>>(deg, scanned, bsum);
        scan2<<<1, 128, 0, stream>>>(bsum, NBLK_SCAN);
        scan3<<<(NN + 255) / 256, 256, 0, stream>>>(deg, scanned, bsum, rowptr[s], cursor);
        fill_csr<<<(EE + 255) / 256, 256, 0, stream>>>(eidx[s], eidx[s] + EE, cursor, csrc[s]);
    }
    seg_starts<<<(NN + 255) / 256, 256, 0, stream>>>(batch, gstart);
    hipMemsetAsync(stats, 0, 48 * 256 * sizeof(float), stream);
    hipMemsetAsync(S, 0, (size_t)GG * 384 * sizeof(float), stream);
    hipMemsetAsync(ccb, 0, (size_t)GG * 128 * sizeof(float), stream);

    const dim3 gemm_grid((NN + 63) / 64, 1);

    // ---- 6 GIN layers ----
    for (int l = 0; l < 6; ++l) {
        for (int k = 0; k < 3; ++k) {
            const float* Ain = (l == 0) ? x : h;
            const int K1 = (l == 0) ? FIN : 128;
            const float* W1 = (l == 0) ? conv1_W1 + (size_t)k * FIN * 128
                                       : conv_rest_W1 + (size_t)((l - 1) * 3 + k) * 128 * 128;
            const float* b1 = (l == 0) ? conv1_b1 + k * 128
                                       : conv_rest_b1 + ((l - 1) * 3 + k) * 128;
            const int lk = l * 3 + k;
            float* slot0 = stats + (size_t)(l * 8 + k * 2) * 256;
            float* slot1 = stats + (size_t)(l * 8 + k * 2 + 1) * 256;

            // proj = Ain @ W1  (no bias; linearity lets us aggregate post-projection)
            gemm_f32<false><<<gemm_grid, 256, 0, stream>>>(
                Ain, W1, nullptr, t1, NN, K1, 128, 0, nullptr);
            // agg[dst] = sum proj[src]
            aggregate<<<(NN * 64 + 255) / 256, 256, 0, stream>>>(t1, rowptr[k], csrc[k], t2);
            // z = (1+eps)*proj + agg + b1  (+BN stats)
            combine_z_stats<<<1024, 256, 0, stream>>>(t1, t2, b1, conv_eps, lk, slot0);
            bn_relu<<<(NN * 128 + 255) / 256, 256, 0, stream>>>(
                t1, slot0, conv_bn1_g + lk * 128, conv_bn1_b + lk * 128, t1, 128, 0);
            // second conv MLP layer (+fused BN stats)
            gemm_f32<false><<<gemm_grid, 256, 0, stream>>>(
                t1, conv_W2 + (size_t)lk * 128 * 128, conv_b2 + lk * 128, t2,
                NN, 128, 128, 1, slot1);
            bn_relu<<<(NN * 128 + 255) / 256, 256, 0, stream>>>(
                t2, slot1, conv_bn2_g + lk * 128, conv_bn2_b + lk * 128,
                xcat, 384, k * 128);
        }
        float* slotF1 = stats + (size_t)(l * 8 + 6) * 256;
        float* slotF2 = stats + (size_t)(l * 8 + 7) * 256;
        gemm_f32<false><<<gemm_grid, 256, 0, stream>>>(
            xcat, mlp_W1 + (size_t)l * 384 * 128, mlp_b1 + l * 128, t1,
            NN, 384, 128, 1, slotF1);
        bn_relu<<<(NN * 128 + 255) / 256, 256, 0, stream>>>(
            t1, slotF1, mlp_bn1_g + l * 128, mlp_bn1_b + l * 128, t1, 128, 0);
        gemm_f32<false><<<gemm_grid, 256, 0, stream>>>(
            t1, mlp_W2 + (size_t)l * 128 * 128, mlp_b2 + l * 128, t2,
            NN, 128, 128, 1, slotF2);
        bn_relu<<<(NN * 128 + 255) / 256, 256, 0, stream>>>(
            t2, slotF2, mlp_bn2_g + l * 128, mlp_bn2_b + l * 128, h, 128, 0);
    }

    // ---- Set2Set readout ----
    pack_wcat<<<(512 * 384 + 255) / 256, 256, 0, stream>>>(lstm_Wih, lstm_Whh, Wcat);
    for (int t = 0; t < 6; ++t) {
        gemm_f32<true><<<dim3(8, 4), 256, 0, stream>>>(
            S, Wcat, nullptr, gates, GG, 384, 512, 0, nullptr);
        lstm_kernel<<<(GG * 128 + 255) / 256, 256, 0, stream>>>(
            gates, lstm_bih, lstm_bhh, ccb, S);
        attend_kernel<<<GG, 256, 0, stream>>>(h, S, ews, gstart);
    }
    fc1_kernel<<<GG, 128, 0, stream>>>(S, fc1_W, fc1_b, gates);
    fc4_kernel<<<(GG * 12 + 255) / 256, 256, 0, stream>>>(gates, fc4_W, fc4_b, outp);
}

// Round 3
// 6535.516 us; speedup vs baseline: 1.5156x; 1.5156x over previous
//
#include <hip/hip_runtime.h>
#include <cstdint>
#include <cstddef>

#define NN 50000
#define EE 1600000
#define GG 512
#define FIN 1273

typedef unsigned short u16;
typedef unsigned int u32;
typedef __attribute__((ext_vector_type(8))) short short8;
typedef __attribute__((ext_vector_type(4))) float f32x4;

__device__ __forceinline__ float sigmf(float x) { return 1.f / (1.f + expf(-x)); }

// truncation split: v == hi + rem exactly; lo = trunc_bf16(rem); |v-(hi+lo)| <= 2^-16 |v|
__device__ __forceinline__ void splitbf(float v, u16& hi, u16& lo) {
    const u32 u = __float_as_uint(v);
    hi = (u16)(u >> 16);
    const float rem = v - __uint_as_float(u & 0xffff0000u);
    lo = (u16)(__float_as_uint(rem) >> 16);
}

__device__ __forceinline__ float hl2f(u16 hi, u16 lo) {
    return __uint_as_float((u32)hi << 16) + __uint_as_float((u32)lo << 16);
}

__device__ __forceinline__ void gload_lds16(const void* g, void* l) {
    __builtin_amdgcn_global_load_lds(
        (const __attribute__((address_space(1))) void*)g,
        (__attribute__((address_space(3))) void*)l, 16, 0, 0);
}

// ========== split-bf16 MFMA GEMM: C[M,128] = A[M,K] * B^T + bias (fp32-accurate)
// A given either as fp32 (AF32=1, split in-register while staging) or as a
// hi/lo bf16 pair (AF32=0, staged via global_load_lds). B always hi/lo pair,
// [128][K] row-major (pre-transposed). acc += Ahi*Bhi + Ahi*Blo + Alo*Bhi.
// Tile 128x128, 4 waves, BK=64, XOR-swizzled LDS (ch ^= row&7).
template <int AF32>
__global__ __launch_bounds__(256) void gemm_split(
    const float* __restrict__ Af,
    const u16* __restrict__ Ahi, const u16* __restrict__ Alo, int lda,
    int K, int Kreal,
    const u16* __restrict__ Bhi, const u16* __restrict__ Blo,
    const float* __restrict__ bias,
    float* __restrict__ C, int M, int do_stats, float* __restrict__ stats)
{
    __shared__ u16 lsAhi[128 * 64];
    __shared__ u16 lsAlo[128 * 64];
    __shared__ u16 lsBhi[128 * 64];
    __shared__ u16 lsBlo[128 * 64];
    const int tid = threadIdx.x;
    const int wave = tid >> 6, lane = tid & 63;
    const int row0 = blockIdx.x * 128;
    const int wm = wave >> 1, wn = wave & 1;
    f32x4 acc[4][4] = {};

    for (int k0 = 0; k0 < K; k0 += 64) {
        if (k0) __syncthreads();
        if (AF32) {
            #pragma unroll
            for (int i = 0; i < 4; ++i) {
                const int slot = i * 256 + tid;
                const int r = slot >> 3, ch = slot & 7;
                int gr = row0 + r; if (gr >= M) gr = M - 1;
                const int kbase = k0 + ch * 8;
                const float* src = Af + (size_t)gr * lda + kbase;
                u16 th[8], tl[8];
                #pragma unroll
                for (int e = 0; e < 8; ++e) {
                    const float v = (kbase + e < Kreal) ? src[e] : 0.f;
                    splitbf(v, th[e], tl[e]);
                }
                const int off = (r << 6) + ((ch ^ (r & 7)) << 3);
                *(short8*)&lsAhi[off] = *(const short8*)th;
                *(short8*)&lsAlo[off] = *(const short8*)tl;
            }
        } else {
            #pragma unroll
            for (int i = 0; i < 4; ++i) {
                const int slot = i * 256 + wave * 64 + lane;
                const int r = slot >> 3, ch = slot & 7;
                const int sch = ch ^ (r & 7);
                int gr = row0 + r; if (gr >= M) gr = M - 1;
                const size_t goff = (size_t)gr * lda + k0 + sch * 8;
                const int lbase = (i * 256 + wave * 64) * 8;
                gload_lds16(Ahi + goff, &lsAhi[lbase]);
                gload_lds16(Alo + goff, &lsAlo[lbase]);
            }
        }
        {   // B tiles
            #pragma unroll
            for (int i = 0; i < 4; ++i) {
                const int slot = i * 256 + wave * 64 + lane;
                const int r = slot >> 3, ch = slot & 7;
                const int sch = ch ^ (r & 7);
                const size_t goff = (size_t)r * K + k0 + sch * 8;
                const int lbase = (i * 256 + wave * 64) * 8;
                gload_lds16(Bhi + goff, &lsBhi[lbase]);
                gload_lds16(Blo + goff, &lsBlo[lbase]);
            }
        }
        __syncthreads();
        #pragma unroll
        for (int ks = 0; ks < 2; ++ks) {
            short8 ah[4], al[4], bh[4], bl[4];
            const int kch = ks * 4 + (lane >> 4);
            #pragma unroll
            for (int m = 0; m < 4; ++m) {
                const int r = wm * 64 + m * 16 + (lane & 15);
                const int off = (r << 6) + ((kch ^ (r & 7)) << 3);
                ah[m] = *(const short8*)&lsAhi[off];
                al[m] = *(const short8*)&lsAlo[off];
            }
            #pragma unroll
            for (int n = 0; n < 4; ++n) {
                const int c = wn * 64 + n * 16 + (lane & 15);
                const int off = (c << 6) + ((kch ^ (c & 7)) << 3);
                bh[n] = *(const short8*)&lsBhi[off];
                bl[n] = *(const short8*)&lsBlo[off];
            }
            #pragma unroll
            for (int m = 0; m < 4; ++m)
                #pragma unroll
                for (int n = 0; n < 4; ++n) {
                    acc[m][n] = __builtin_amdgcn_mfma_f32_16x16x32_bf16(
                        ah[m], bh[n], acc[m][n], 0, 0, 0);
                    acc[m][n] = __builtin_amdgcn_mfma_f32_16x16x32_bf16(
                        ah[m], bl[n], acc[m][n], 0, 0, 0);
                    acc[m][n] = __builtin_amdgcn_mfma_f32_16x16x32_bf16(
                        al[m], bh[n], acc[m][n], 0, 0, 0);
                }
        }
    }

    // epilogue: bias, fp32 store, per-column stats
    float colsum[4] = {0.f, 0.f, 0.f, 0.f}, colsq[4] = {0.f, 0.f, 0.f, 0.f};
    #pragma unroll
    for (int n = 0; n < 4; ++n) {
        const int c = wn * 64 + n * 16 + (lane & 15);
        const float bv = bias ? bias[c] : 0.f;
        #pragma unroll
        for (int m = 0; m < 4; ++m) {
            #pragma unroll
            for (int j = 0; j < 4; ++j) {
                const int gr = row0 + wm * 64 + m * 16 + ((lane >> 4) << 2) + j;
                if (gr < M) {
                    const float v = acc[m][n][j] + bv;
                    C[(size_t)gr * 128 + c] = v;
                    colsum[n] += v; colsq[n] += v * v;
                }
            }
        }
    }
    if (do_stats) {
        float* ssum = (float*)lsAhi;       // reuse tile LDS (keeps block at 64 KB)
        float* ssq  = ssum + 128;
        __syncthreads();                   // all frag reads done
        if (tid < 128) { ssum[tid] = 0.f; ssq[tid] = 0.f; }
        __syncthreads();
        #pragma unroll
        for (int n = 0; n < 4; ++n) {
            const int c = wn * 64 + n * 16 + (lane & 15);
            atomicAdd(&ssum[c], colsum[n]);
            atomicAdd(&ssq[c], colsq[n]);
        }
        __syncthreads();
        if (tid < 128) {
            atomicAdd(&stats[tid],       ssum[tid]);
            atomicAdd(&stats[128 + tid], ssq[tid]);
        }
    }
}

// ------ weight transpose+split: W[nmat][K][128] -> Whi/Wlo[nmat][128][Kpad] ----
__global__ __launch_bounds__(256) void wt_cast2(const float* __restrict__ W,
                                                u16* __restrict__ Whi,
                                                u16* __restrict__ Wlo,
                                                int total, int K, int Kpad) {
    const int idx = blockIdx.x * 256 + threadIdx.x;
    if (idx >= total) return;
    const int perm = 128 * Kpad;
    const int m = idx / perm, rem = idx - m * perm;
    const int n = rem / Kpad, k = rem - n * Kpad;
    const float v = (k < K) ? W[(size_t)m * K * 128 + (size_t)k * 128 + n] : 0.f;
    u16 hi, lo;
    splitbf(v, hi, lo);
    Whi[idx] = hi; Wlo[idx] = lo;
}

// ---------------- fp32 tiled GEMM (LSTM gates only) ----------------------------
template <bool BT>
__global__ __launch_bounds__(256) void gemm_f32(
    const float* __restrict__ A, const float* __restrict__ B,
    const float* __restrict__ bias, float* __restrict__ C,
    int M, int K, int Nc)
{
    __shared__ float As[32][68];
    __shared__ float Bs[32][132];
    const int tid = threadIdx.x;
    const int tx = tid & 15, ty = tid >> 4;
    const int row0 = blockIdx.x * 64, col0 = blockIdx.y * 128;
    float acc[4][8] = {};
    for (int k0 = 0; k0 < K; k0 += 32) {
        {
            const int kk = tid & 31, rb = tid >> 5;
            #pragma unroll
            for (int i = 0; i < 8; ++i) {
                const int r = rb + i * 8, gr = row0 + r, gk = k0 + kk;
                As[kk][r] = (gr < M && gk < K) ? A[(size_t)gr * K + gk] : 0.f;
            }
        }
        if (!BT) {
            const int c = tid & 127, kb = tid >> 7;
            #pragma unroll
            for (int i = 0; i < 16; ++i) {
                const int kk = kb + i * 2, gk = k0 + kk;
                Bs[kk][c] = (gk < K) ? B[(size_t)gk * Nc + col0 + c] : 0.f;
            }
        } else {
            const int kk = tid & 31, cb = tid >> 5;
            #pragma unroll
            for (int i = 0; i < 16; ++i) {
                const int c = cb + i * 8, gk = k0 + kk;
                Bs[kk][c] = (gk < K) ? B[(size_t)(col0 + c) * K + gk] : 0.f;
            }
        }
        __syncthreads();
        #pragma unroll 8
        for (int kk = 0; kk < 32; ++kk) {
            const float4 av  = *(const float4*)&As[kk][ty * 4];
            const float4 bv0 = *(const float4*)&Bs[kk][tx * 8];
            const float4 bv1 = *(const float4*)&Bs[kk][tx * 8 + 4];
            const float a[4] = {av.x, av.y, av.z, av.w};
            const float b[8] = {bv0.x, bv0.y, bv0.z, bv0.w, bv1.x, bv1.y, bv1.z, bv1.w};
            #pragma unroll
            for (int i = 0; i < 4; ++i)
                #pragma unroll
                for (int j = 0; j < 8; ++j)
                    acc[i][j] = fmaf(a[i], b[j], acc[i][j]);
        }
        __syncthreads();
    }
    #pragma unroll
    for (int j = 0; j < 8; ++j) {
        const float bv = bias ? bias[col0 + tx * 8 + j] : 0.f;
        #pragma unroll
        for (int i = 0; i < 4; ++i) acc[i][j] += bv;
    }
    #pragma unroll
    for (int i = 0; i < 4; ++i) {
        const int gr = row0 + ty * 4 + i;
        if (gr < M) {
            *(float4*)&C[(size_t)gr * Nc + col0 + tx * 8] =
                make_float4(acc[i][0], acc[i][1], acc[i][2], acc[i][3]);
            *(float4*)&C[(size_t)gr * Nc + col0 + tx * 8 + 4] =
                make_float4(acc[i][4], acc[i][5], acc[i][6], acc[i][7]);
        }
    }
}

// ---------------- CSR build (counting sort by destination) ---------------------
__global__ __launch_bounds__(256) void count_deg(const int* __restrict__ dst,
                                                 int* __restrict__ deg) {
    const int e = blockIdx.x * 256 + threadIdx.x;
    if (e < EE) atomicAdd(&deg[dst[e]], 1);
}

__global__ __launch_bounds__(512) void scan1(const int* __restrict__ deg,
                                             int* __restrict__ scanned,
                                             int* __restrict__ bsum) {
    __shared__ int s[512];
    const int t = threadIdx.x;
    const int i = blockIdx.x * 512 + t;
    const int v = (i < NN) ? deg[i] : 0;
    s[t] = v; __syncthreads();
    for (int o = 1; o < 512; o <<= 1) {
        const int tv = (t >= o) ? s[t - o] : 0;
        __syncthreads();
        s[t] += tv;
        __syncthreads();
    }
    if (i < NN) scanned[i] = s[t];
    if (t == 511) bsum[blockIdx.x] = s[511];
}

__global__ __launch_bounds__(128) void scan2(int* __restrict__ bsum, int nb) {
    __shared__ int s[128];
    const int t = threadIdx.x;
    const int v = (t < nb) ? bsum[t] : 0;
    s[t] = v; __syncthreads();
    for (int o = 1; o < 128; o <<= 1) {
        const int tv = (t >= o) ? s[t - o] : 0;
        __syncthreads();
        s[t] += tv;
        __syncthreads();
    }
    if (t < nb) bsum[t] = s[t] - v;  // exclusive
}

__global__ __launch_bounds__(256) void scan3(const int* __restrict__ deg,
                                             const int* __restrict__ scanned,
                                             const int* __restrict__ bsum,
                                             int* __restrict__ rowptr,
                                             int* __restrict__ cursor) {
    const int i = blockIdx.x * 256 + threadIdx.x;
    if (i < NN) {
        const int v = bsum[i >> 9] + scanned[i] - deg[i];
        rowptr[i] = v; cursor[i] = v;
    }
    if (i == 0) rowptr[NN] = EE;
}

__global__ __launch_bounds__(256) void fill_csr(const int* __restrict__ src,
                                                const int* __restrict__ dst,
                                                int* __restrict__ cursor,
                                                int* __restrict__ csrc) {
    const int e = blockIdx.x * 256 + threadIdx.x;
    if (e < EE) {
        const int pos = atomicAdd(&cursor[dst[e]], 1);
        csrc[pos] = src[e];
    }
}

// --------- fp32 neighbor aggregation: one wave per destination node ------------
__global__ __launch_bounds__(256) void aggregate_f32(const float* __restrict__ proj,
                                                     const int* __restrict__ rowptr,
                                                     const int* __restrict__ csrc,
                                                     float* __restrict__ agg) {
    const int wid = (int)((blockIdx.x * 256 + threadIdx.x) >> 6);
    const int lane = threadIdx.x & 63;
    if (wid >= NN) return;
    const int s0 = rowptr[wid], s1 = rowptr[wid + 1];
    const float2* p2 = (const float2*)proj;
    float ax = 0.f, ay = 0.f;
    int j = s0;
    for (; j + 3 < s1; j += 4) {
        const float2 v0 = p2[(size_t)csrc[j] * 64 + lane];
        const float2 v1 = p2[(size_t)csrc[j + 1] * 64 + lane];
        const float2 v2 = p2[(size_t)csrc[j + 2] * 64 + lane];
        const float2 v3 = p2[(size_t)csrc[j + 3] * 64 + lane];
        ax += v0.x + v1.x + v2.x + v3.x;
        ay += v0.y + v1.y + v2.y + v3.y;
    }
    for (; j < s1; ++j) {
        const float2 v = p2[(size_t)csrc[j] * 64 + lane];
        ax += v.x; ay += v.y;
    }
    ((float2*)agg)[(size_t)wid * 64 + lane] = make_float2(ax, ay);
}

// ------------- z = (1+eps)*proj + agg + b1 (in-place) + BN stats ---------------
__global__ __launch_bounds__(256) void combine_z_stats(
    float* __restrict__ z, const float* __restrict__ agg,
    const float* __restrict__ b1, const float* __restrict__ eps_arr, int eps_idx,
    float* __restrict__ stats)
{
    const float e1 = 1.f + eps_arr[eps_idx];
    const int gt = blockIdx.x * 256 + threadIdx.x;
    const int d = gt & 127;
    const float bv = b1[d];
    const size_t stride = 1024 * 256;
    float s = 0.f, q = 0.f;
    for (size_t i = gt; i < (size_t)NN * 128; i += stride) {
        const float v = fmaf(e1, z[i], agg[i] + bv);
        z[i] = v; s += v; q += v * v;
    }
    atomicAdd(&stats[d], s);
    atomicAdd(&stats[128 + d], q);
}

// ------- BN (batch stats) + ReLU -> hi/lo bf16 pair (strided) ------------------
__global__ __launch_bounds__(256) void bn_relu2(
    const float* __restrict__ xin, const float* __restrict__ stats,
    const float* __restrict__ gamma, const float* __restrict__ beta,
    u16* __restrict__ ohi, u16* __restrict__ olo, int ostride, int ooff)
{
    const size_t i = (size_t)blockIdx.x * 256 + threadIdx.x;  // pair index
    if (i >= (size_t)NN * 64) return;
    const int d = (int)(i & 63) * 2;
    const size_t n = i >> 6;
    const float inv_n = 1.f / NN;
    const float mu0 = stats[d] * inv_n,     mu1 = stats[d + 1] * inv_n;
    const float v0 = fmaxf(stats[128 + d] * inv_n - mu0 * mu0, 0.f);
    const float v1 = fmaxf(stats[129 + d] * inv_n - mu1 * mu1, 0.f);
    const float s0 = gamma[d] * rsqrtf(v0 + 1e-5f);
    const float s1 = gamma[d + 1] * rsqrtf(v1 + 1e-5f);
    const float2 xv = ((const float2*)xin)[i];
    const float y0 = fmaxf(fmaf(s0, xv.x - mu0, beta[d]), 0.f);
    const float y1 = fmaxf(fmaf(s1, xv.y - mu1, beta[d + 1]), 0.f);
    u16 h0, l0, h1, l1;
    splitbf(y0, h0, l0);
    splitbf(y1, h1, l1);
    const size_t o = n * (size_t)ostride + ooff + d;
    *(u32*)&ohi[o] = (u32)h0 | ((u32)h1 << 16);
    *(u32*)&olo[o] = (u32)l0 | ((u32)l1 << 16);
}

// ---------------- per-graph segment starts (batch is sorted) -------------------
__global__ __launch_bounds__(256) void seg_starts(const int* __restrict__ batch,
                                                  int* __restrict__ gstart) {
    const int i = blockIdx.x * 256 + threadIdx.x;
    if (i >= NN) return;
    const int b = batch[i];
    if (i == 0) { for (int g = 0; g <= b; ++g) gstart[g] = 0; }
    else {
        const int pb = batch[i - 1];
        for (int g = pb + 1; g <= b; ++g) gstart[g] = i;
    }
    if (i == NN - 1) { for (int g = b + 1; g <= GG; ++g) gstart[g] = NN; }
}

// ---------------- Set2Set ------------------------------------------------------
__global__ __launch_bounds__(256) void pack_wcat(const float* __restrict__ Wih,
                                                 const float* __restrict__ Whh,
                                                 float* __restrict__ Wcat) {
    const int i = blockIdx.x * 256 + threadIdx.x;
    if (i >= 512 * 384) return;
    const int j = i / 384, k = i - j * 384;
    Wcat[i] = (k < 256) ? Wih[j * 256 + k] : Whh[j * 128 + (k - 256)];
}

__global__ __launch_bounds__(256) void lstm_kernel(
    const float* __restrict__ gates, const float* __restrict__ bih,
    const float* __restrict__ bhh, float* __restrict__ cc, float* __restrict__ S)
{
    const int i = blockIdx.x * 256 + threadIdx.x;
    if (i >= GG * 128) return;
    const int g = i >> 7, d = i & 127;
    const float* gr = gates + (size_t)g * 512;
    const float ig = gr[d]       + bih[d]       + bhh[d];
    const float fg = gr[128 + d] + bih[128 + d] + bhh[128 + d];
    const float gv = gr[256 + d] + bih[256 + d] + bhh[256 + d];
    const float og = gr[384 + d] + bih[384 + d] + bhh[384 + d];
    const float c  = sigmf(fg) * cc[i] + sigmf(ig) * tanhf(gv);
    const float hv = sigmf(og) * tanhf(c);
    cc[i] = c;
    S[(size_t)g * 384 + d] = hv;
    S[(size_t)g * 384 + 256 + d] = hv;
}

// per-graph attention over h given as hi/lo bf16 pair
__global__ __launch_bounds__(256) void attend_kernel(
    const u16* __restrict__ hhi, const u16* __restrict__ hlo,
    float* __restrict__ S, float* __restrict__ ews, const int* __restrict__ gstart)
{
    const int g = blockIdx.x;
    const int rs = gstart[g], re = gstart[g + 1];
    const int tid = threadIdx.x, lane = tid & 63, w = tid >> 6;
    __shared__ float q[128];
    __shared__ float red[8];
    if (tid < 128) q[tid] = S[(size_t)g * 384 + 256 + tid];
    __syncthreads();
    float lmax = -1e30f;
    for (int n = rs + w; n < re; n += 4) {
        const u32 vh = ((const u32*)hhi)[(size_t)n * 64 + lane];
        const u32 vl = ((const u32*)hlo)[(size_t)n * 64 + lane];
        const float e0 = __uint_as_float(vh << 16) + __uint_as_float(vl << 16);
        const float e1 = __uint_as_float(vh & 0xffff0000u) + __uint_as_float(vl & 0xffff0000u);
        float p = e0 * q[2 * lane] + e1 * q[2 * lane + 1];
        #pragma unroll
        for (int o = 32; o; o >>= 1) p += __shfl_down(p, o, 64);
        if (lane == 0) { ews[n] = p; lmax = fmaxf(lmax, p); }
    }
    if (lane == 0) red[w] = lmax;
    __syncthreads();
    const float m = fmaxf(fmaxf(red[0], red[1]), fmaxf(red[2], red[3]));
    __syncthreads();
    float lsum = 0.f;
    for (int n = rs + tid; n < re; n += 256) {
        const float ex = expf(ews[n] - m);
        ews[n] = ex; lsum += ex;
    }
    #pragma unroll
    for (int o = 32; o; o >>= 1) lsum += __shfl_down(lsum, o, 64);
    if (lane == 0) red[w] = lsum;
    __syncthreads();
    const float denom = red[0] + red[1] + red[2] + red[3];
    if (tid < 128) {
        float acc = 0.f;
        for (int n = rs; n < re; ++n)
            acc = fmaf(ews[n], hl2f(hhi[(size_t)n * 128 + tid],
                                    hlo[(size_t)n * 128 + tid]), acc);
        S[(size_t)g * 384 + 128 + tid] = (denom > 0.f) ? acc / denom : 0.f;
    }
}

__global__ __launch_bounds__(128) void fc1_kernel(const float* __restrict__ S,
                                                  const float* __restrict__ W,
                                                  const float* __restrict__ b,
                                                  float* __restrict__ out1) {
    const int g = blockIdx.x, d = threadIdx.x;
    __shared__ float qs[256];
    qs[d] = S[(size_t)g * 384 + d];
    qs[128 + d] = S[(size_t)g * 384 + 128 + d];
    __syncthreads();
    float acc = b[d];
    for (int k = 0; k < 256; ++k) acc = fmaf(qs[k], W[k * 128 + d], acc);
    out1[(size_t)g * 128 + d] = fmaxf(acc, 0.f);
}

__global__ __launch_bounds__(256) void fc4_kernel(const float* __restrict__ out1,
                                                  const float* __restrict__ W,
                                                  const float* __restrict__ b,
                                                  float* __restrict__ out) {
    const int i = blockIdx.x * 256 + threadIdx.x;
    if (i >= GG * 12) return;
    const int g = i / 12, j = i - g * 12;
    float acc = b[j];
    for (int d = 0; d < 128; ++d)
        acc = fmaf(out1[(size_t)g * 128 + d], W[d * 12 + j], acc);
    out[i] = acc;
}

// ================================================================================
extern "C" void kernel_launch(void* const* d_in, const int* in_sizes, int n_in,
                              void* d_out, int out_size, void* d_ws, size_t ws_size,
                              hipStream_t stream)
{
    const float* x        = (const float*)d_in[0];
    const int*   eidx[3]  = {(const int*)d_in[1], (const int*)d_in[2], (const int*)d_in[3]};
    const int*   batch    = (const int*)d_in[4];
    const float* conv1_W1     = (const float*)d_in[5];
    const float* conv1_b1     = (const float*)d_in[6];
    const float* conv_rest_W1 = (const float*)d_in[7];
    const float* conv_rest_b1 = (const float*)d_in[8];
    const float* conv_W2      = (const float*)d_in[9];
    const float* conv_b2      = (const float*)d_in[10];
    const float* conv_bn1_g   = (const float*)d_in[11];
    const float* conv_bn1_b   = (const float*)d_in[12];
    const float* conv_bn2_g   = (const float*)d_in[13];
    const float* conv_bn2_b   = (const float*)d_in[14];
    const float* conv_eps     = (const float*)d_in[15];
    const float* mlp_W1       = (const float*)d_in[16];
    const float* mlp_b1       = (const float*)d_in[17];
    const float* mlp_bn1_g    = (const float*)d_in[18];
    const float* mlp_bn1_b    = (const float*)d_in[19];
    const float* mlp_W2       = (const float*)d_in[20];
    const float* mlp_b2       = (const float*)d_in[21];
    const float* mlp_bn2_g    = (const float*)d_in[22];
    const float* mlp_bn2_b    = (const float*)d_in[23];
    const float* lstm_Wih     = (const float*)d_in[24];
    const float* lstm_Whh     = (const float*)d_in[25];
    const float* lstm_bih     = (const float*)d_in[26];
    const float* lstm_bhh     = (const float*)d_in[27];
    const float* fc1_W        = (const float*)d_in[28];
    const float* fc1_b        = (const float*)d_in[29];
    const float* fc4_W        = (const float*)d_in[30];
    const float* fc4_b        = (const float*)d_in[31];
    float* outp = (float*)d_out;

    // ---- workspace layout ----
    float* f = (float*)d_ws;
    size_t fo = 0;
    float* t1    = f + fo; fo += (size_t)NN * 128;
    float* t2    = f + fo; fo += (size_t)NN * 128;
    float* ews   = f + fo; fo += NN;
    float* stats = f + fo; fo += 48 * 256;
    float* S     = f + fo; fo += (size_t)GG * 384;
    float* ccb   = f + fo; fo += (size_t)GG * 128;
    float* gates = f + fo; fo += (size_t)GG * 512;  // reused as fc1 output
    float* Wcat  = f + fo; fo += (size_t)512 * 384;
    fo = (fo + 7) & ~(size_t)7;   // 16B-align bf16 region
    u16* b = (u16*)(f + fo);
    size_t bo = 0;
    u16* act_hi  = b + bo; bo += (size_t)NN * 128;
    u16* act_lo  = b + bo; bo += (size_t)NN * 128;
    u16* xcat_hi = b + bo; bo += (size_t)NN * 384;
    u16* xcat_lo = b + bo; bo += (size_t)NN * 384;
    u16* h_hi    = b + bo; bo += (size_t)NN * 128;
    u16* h_lo    = b + bo; bo += (size_t)NN * 128;
    u16* c1_hi   = b + bo; bo += (size_t)3 * 128 * 1280;
    u16* c1_lo   = b + bo; bo += (size_t)3 * 128 * 1280;
    u16* rw1_hi  = b + bo; bo += (size_t)15 * 128 * 128;
    u16* rw1_lo  = b + bo; bo += (size_t)15 * 128 * 128;
    u16* w2_hi   = b + bo; bo += (size_t)18 * 128 * 128;
    u16* w2_lo   = b + bo; bo += (size_t)18 * 128 * 128;
    u16* mw1_hi  = b + bo; bo += (size_t)6 * 128 * 384;
    u16* mw1_lo  = b + bo; bo += (size_t)6 * 128 * 384;
    u16* mw2_hi  = b + bo; bo += (size_t)6 * 128 * 128;
    u16* mw2_lo  = b + bo; bo += (size_t)6 * 128 * 128;
    int* ip = (int*)(b + bo);
    size_t io = 0;
    int* rowptr[3]; int* csrc[3];
    for (int s = 0; s < 3; ++s) { rowptr[s] = ip + io; io += NN + 1; }
    for (int s = 0; s < 3; ++s) { csrc[s]   = ip + io; io += EE; }
    int* deg     = ip + io; io += NN;
    int* cursor  = ip + io; io += NN;
    int* scanned = ip + io; io += NN;
    int* bsum    = ip + io; io += 128;
    int* gstart  = ip + io; io += GG + 1;
    const size_t need = fo * 4 + bo * 2 + io * 4;
    if (ws_size < need) return;

    const int NBLK_SCAN = (NN + 511) / 512;

    // ---- weight transpose+split (K padded to x64) ----
    {
        int t;
        t = 3 * 128 * 1280;
        wt_cast2<<<(t + 255) / 256, 256, 0, stream>>>(conv1_W1, c1_hi, c1_lo, t, FIN, 1280);
        t = 15 * 128 * 128;
        wt_cast2<<<(t + 255) / 256, 256, 0, stream>>>(conv_rest_W1, rw1_hi, rw1_lo, t, 128, 128);
        t = 18 * 128 * 128;
        wt_cast2<<<(t + 255) / 256, 256, 0, stream>>>(conv_W2, w2_hi, w2_lo, t, 128, 128);
        t = 6 * 128 * 384;
        wt_cast2<<<(t + 255) / 256, 256, 0, stream>>>(mlp_W1, mw1_hi, mw1_lo, t, 384, 384);
        t = 6 * 128 * 128;
        wt_cast2<<<(t + 255) / 256, 256, 0, stream>>>(mlp_W2, mw2_hi, mw2_lo, t, 128, 128);
    }

    // ---- CSR build for the 3 edge sets ----
    for (int s = 0; s < 3; ++s) {
        hipMemsetAsync(deg, 0, NN * sizeof(int), stream);
        count_deg<<<(EE + 255) / 256, 256, 0, stream>>>(eidx[s] + EE, deg);
        scan1<<<NBLK_SCAN, 512, 0, stream>>>(deg, scanned, bsum);
        scan2<<<1, 128, 0, stream>>>(bsum, NBLK_SCAN);
        scan3<<<(NN + 255) / 256, 256, 0, stream>>>(deg, scanned, bsum, rowptr[s], cursor);
        fill_csr<<<(EE + 255) / 256, 256, 0, stream>>>(eidx[s], eidx[s] + EE, cursor, csrc[s]);
    }
    seg_starts<<<(NN + 255) / 256, 256, 0, stream>>>(batch, gstart);
    hipMemsetAsync(stats, 0, 48 * 256 * sizeof(float), stream);
    hipMemsetAsync(S, 0, (size_t)GG * 384 * sizeof(float), stream);
    hipMemsetAsync(ccb, 0, (size_t)GG * 128 * sizeof(float), stream);

    const int GEMM_GRID = (NN + 127) / 128;   // 391
    const int BN_GRID = (NN * 64 + 255) / 256;
    const int AGG_GRID = (NN * 64 + 255) / 256;

    // ---- 6 GIN layers ----
    for (int l = 0; l < 6; ++l) {
        for (int k = 0; k < 3; ++k) {
            const int lk = l * 3 + k;
            const float* b1 = (l == 0) ? conv1_b1 + k * 128
                                       : conv_rest_b1 + ((l - 1) * 3 + k) * 128;
            float* slot0 = stats + (size_t)(l * 8 + k * 2) * 256;
            float* slot1 = stats + (size_t)(l * 8 + k * 2 + 1) * 256;

            if (l == 0)
                gemm_split<1><<<GEMM_GRID, 256, 0, stream>>>(
                    x, nullptr, nullptr, FIN, 1280, FIN,
                    c1_hi + (size_t)k * 128 * 1280, c1_lo + (size_t)k * 128 * 1280,
                    nullptr, t1, NN, 0, nullptr);
            else
                gemm_split<0><<<GEMM_GRID, 256, 0, stream>>>(
                    nullptr, h_hi, h_lo, 128, 128, 128,
                    rw1_hi + (size_t)((l - 1) * 3 + k) * 128 * 128,
                    rw1_lo + (size_t)((l - 1) * 3 + k) * 128 * 128,
                    nullptr, t1, NN, 0, nullptr);
            aggregate_f32<<<AGG_GRID, 256, 0, stream>>>(t1, rowptr[k], csrc[k], t2);
            combine_z_stats<<<1024, 256, 0, stream>>>(t1, t2, b1, conv_eps, lk, slot0);
            bn_relu2<<<BN_GRID, 256, 0, stream>>>(
                t1, slot0, conv_bn1_g + lk * 128, conv_bn1_b + lk * 128,
                act_hi, act_lo, 128, 0);
            gemm_split<0><<<GEMM_GRID, 256, 0, stream>>>(
                nullptr, act_hi, act_lo, 128, 128, 128,
                w2_hi + (size_t)lk * 128 * 128, w2_lo + (size_t)lk * 128 * 128,
                conv_b2 + lk * 128, t2, NN, 1, slot1);
            bn_relu2<<<BN_GRID, 256, 0, stream>>>(
                t2, slot1, conv_bn2_g + lk * 128, conv_bn2_b + lk * 128,
                xcat_hi, xcat_lo, 384, k * 128);
        }
        float* slotF1 = stats + (size_t)(l * 8 + 6) * 256;
        float* slotF2 = stats + (size_t)(l * 8 + 7) * 256;
        gemm_split<0><<<GEMM_GRID, 256, 0, stream>>>(
            nullptr, xcat_hi, xcat_lo, 384, 384, 384,
            mw1_hi + (size_t)l * 128 * 384, mw1_lo + (size_t)l * 128 * 384,
            mlp_b1 + l * 128, t1, NN, 1, slotF1);
        bn_relu2<<<BN_GRID, 256, 0, stream>>>(
            t1, slotF1, mlp_bn1_g + l * 128, mlp_bn1_b + l * 128,
            act_hi, act_lo, 128, 0);
        gemm_split<0><<<GEMM_GRID, 256, 0, stream>>>(
            nullptr, act_hi, act_lo, 128, 128, 128,
            mw2_hi + (size_t)l * 128 * 128, mw2_lo + (size_t)l * 128 * 128,
            mlp_b2 + l * 128, t2, NN, 1, slotF2);
        bn_relu2<<<BN_GRID, 256, 0, stream>>>(
            t2, slotF2, mlp_bn2_g + l * 128, mlp_bn2_b + l * 128,
            h_hi, h_lo, 128, 0);
    }

    // ---- Set2Set readout (fp32) ----
    pack_wcat<<<(512 * 384 + 255) / 256, 256, 0, stream>>>(lstm_Wih, lstm_Whh, Wcat);
    for (int t = 0; t < 6; ++t) {
        gemm_f32<true><<<dim3(8, 4), 256, 0, stream>>>(
            S, Wcat, nullptr, gates, GG, 384, 512);
        lstm_kernel<<<(GG * 128 + 255) / 256, 256, 0, stream>>>(
            gates, lstm_bih, lstm_bhh, ccb, S);
        attend_kernel<<<GG, 256, 0, stream>>>(h_hi, h_lo, S, ews, gstart);
    }
    fc1_kernel<<<GG, 128, 0, stream>>>(S, fc1_W, fc1_b, gates);
    fc4_kernel<<<(GG * 12 + 255) / 256, 256, 0, stream>>>(gates, fc4_W, fc4_b, outp);
}

// Round 4
// 6490.605 us; speedup vs baseline: 1.5261x; 1.0069x over previous
//
#include <hip/hip_runtime.h>
#include <cstdint>
#include <cstddef>

#define NN 50000
#define EE 1600000
#define GG 512
#define FIN 1273

typedef unsigned short u16;
typedef unsigned int u32;
typedef __attribute__((ext_vector_type(8))) short short8;
typedef __attribute__((ext_vector_type(4))) float f32x4;

__device__ __forceinline__ float sigmf(float x) { return 1.f / (1.f + expf(-x)); }

// truncation split: v == hi + rem exactly; lo = bf16(rem); |v-(hi+lo)| <= 2^-16 |v|
__device__ __forceinline__ void splitbf(float v, u16& hi, u16& lo) {
    const u32 u = __float_as_uint(v);
    hi = (u16)(u >> 16);
    const float rem = v - __uint_as_float(u & 0xffff0000u);
    lo = (u16)(__float_as_uint(rem) >> 16);
}

__device__ __forceinline__ void gload_lds16(const void* g, void* l) {
    __builtin_amdgcn_global_load_lds(
        (const __attribute__((address_space(1))) void*)g,
        (__attribute__((address_space(3))) void*)l, 16, 0, 0);
}

// ===== split-bf16 MFMA GEMM with BN+ReLU fused into A staging ==================
// MODE 0: A = fp32 [M][lda], plain split (layer-0 x).
// MODE 1: A = fp32 [M][128], apply y = relu(gamma*inv*(v-mu)+beta) from st0 stats.
// MODE 2: K=384, A columns [0,128)/[128,256)/[256,384) from A0/A1/A2, each with
//         its own stats/gamma/beta (fusion-MLP concat input, never materialized).
// B: [128][K] hi/lo bf16 pair (pre-transposed weights), staged via global_load_lds.
// Tile 64x128, 4 waves (2x2), BK=64, XOR-swizzled LDS (ch ^= row&7).
// Epilogue: bias, fp32 C, optional per-column sum/sumsq -> stats atomics.
template <int MODE>
__global__ __launch_bounds__(256) void gemm_bn(
    const float* __restrict__ A0, const float* __restrict__ A1,
    const float* __restrict__ A2, int lda, int K, int Kreal,
    const float* __restrict__ st0, const float* __restrict__ st1,
    const float* __restrict__ st2,
    const float* __restrict__ g0, const float* __restrict__ g1,
    const float* __restrict__ g2,
    const float* __restrict__ be0, const float* __restrict__ be1,
    const float* __restrict__ be2,
    const u16* __restrict__ Bhi, const u16* __restrict__ Blo,
    const float* __restrict__ bias,
    float* __restrict__ C, int M, int do_stats, float* __restrict__ stats)
{
    __shared__ u16 lsAhi[64 * 64];
    __shared__ u16 lsAlo[64 * 64];
    __shared__ u16 lsBhi[128 * 64];
    __shared__ u16 lsBlo[128 * 64];
    __shared__ float sMu[384], sSc[384], sBt[384];
    const int tid = threadIdx.x;
    const int wave = tid >> 6, lane = tid & 63;
    const int row0 = blockIdx.x * 64;
    const int wm = wave >> 1, wn = wave & 1;
    f32x4 acc[2][4] = {};

    if (MODE) {
        for (int kk = tid; kk < K; kk += 256) {
            const float *st, *ga, *bb;
            if (MODE == 2) {
                const int s = kk >> 7;
                st = s == 0 ? st0 : (s == 1 ? st1 : st2);
                ga = s == 0 ? g0 : (s == 1 ? g1 : g2);
                bb = s == 0 ? be0 : (s == 1 ? be1 : be2);
            } else { st = st0; ga = g0; bb = be0; }
            const int d = kk & 127;
            const float mu = st[d] * (1.f / NN);
            const float var = fmaxf(st[128 + d] * (1.f / NN) - mu * mu, 0.f);
            sMu[kk] = mu;
            sSc[kk] = ga[d] * rsqrtf(var + 1e-5f);
            sBt[kk] = bb[d];
        }
    }
    __syncthreads();

    for (int k0 = 0; k0 < K; k0 += 64) {
        if (k0) __syncthreads();
        // ---- A tile: reg-stage fp32 -> (BN+ReLU) -> hi/lo split -> LDS ----
        #pragma unroll
        for (int i = 0; i < 2; ++i) {
            const int slot = i * 256 + tid;
            const int r = slot >> 3, ch = slot & 7;
            int gr = row0 + r; if (gr >= M) gr = M - 1;
            const int kb = k0 + ch * 8;
            u16 th[8], tl[8];
            if (MODE == 0) {
                const float* src = A0 + (size_t)gr * lda;
                #pragma unroll
                for (int e = 0; e < 8; ++e) {
                    const float v = (kb + e < Kreal) ? src[kb + e] : 0.f;
                    splitbf(v, th[e], tl[e]);
                }
            } else {
                const float* src = (MODE == 2)
                    ? (k0 < 128 ? A0 : (k0 < 256 ? A1 : A2)) : A0;
                const float* rowp = src + (size_t)gr * 128 + (kb & 127);
                #pragma unroll
                for (int e = 0; e < 8; ++e) {
                    const float v = rowp[e];
                    const float y = fmaxf(
                        fmaf(sSc[kb + e], v - sMu[kb + e], sBt[kb + e]), 0.f);
                    splitbf(y, th[e], tl[e]);
                }
            }
            const int off = (r << 6) + ((ch ^ (r & 7)) << 3);
            *(short8*)&lsAhi[off] = *(const short8*)th;
            *(short8*)&lsAlo[off] = *(const short8*)tl;
        }
        // ---- B tile via global_load_lds (pre-swizzled source) ----
        #pragma unroll
        for (int i = 0; i < 4; ++i) {
            const int slot = i * 256 + wave * 64 + lane;
            const int r = slot >> 3, ch = slot & 7;
            const int sch = ch ^ (r & 7);
            const size_t goff = (size_t)r * K + k0 + sch * 8;
            const int lbase = (i * 256 + wave * 64) * 8;
            gload_lds16(Bhi + goff, &lsBhi[lbase]);
            gload_lds16(Blo + goff, &lsBlo[lbase]);
        }
        __syncthreads();
        #pragma unroll
        for (int ks = 0; ks < 2; ++ks) {
            short8 ah[2], al[2], bh[4], bl[4];
            const int kch = ks * 4 + (lane >> 4);
            #pragma unroll
            for (int m = 0; m < 2; ++m) {
                const int r = wm * 32 + m * 16 + (lane & 15);
                const int off = (r << 6) + ((kch ^ (r & 7)) << 3);
                ah[m] = *(const short8*)&lsAhi[off];
                al[m] = *(const short8*)&lsAlo[off];
            }
            #pragma unroll
            for (int n = 0; n < 4; ++n) {
                const int c = wn * 64 + n * 16 + (lane & 15);
                const int off = (c << 6) + ((kch ^ (c & 7)) << 3);
                bh[n] = *(const short8*)&lsBhi[off];
                bl[n] = *(const short8*)&lsBlo[off];
            }
            #pragma unroll
            for (int m = 0; m < 2; ++m)
                #pragma unroll
                for (int n = 0; n < 4; ++n) {
                    acc[m][n] = __builtin_amdgcn_mfma_f32_16x16x32_bf16(
                        ah[m], bh[n], acc[m][n], 0, 0, 0);
                    acc[m][n] = __builtin_amdgcn_mfma_f32_16x16x32_bf16(
                        ah[m], bl[n], acc[m][n], 0, 0, 0);
                    acc[m][n] = __builtin_amdgcn_mfma_f32_16x16x32_bf16(
                        al[m], bh[n], acc[m][n], 0, 0, 0);
                }
        }
    }

    float colsum[4] = {0.f, 0.f, 0.f, 0.f}, colsq[4] = {0.f, 0.f, 0.f, 0.f};
    #pragma unroll
    for (int n = 0; n < 4; ++n) {
        const int c = wn * 64 + n * 16 + (lane & 15);
        const float bv = bias ? bias[c] : 0.f;
        #pragma unroll
        for (int m = 0; m < 2; ++m) {
            #pragma unroll
            for (int j = 0; j < 4; ++j) {
                const int gr = row0 + wm * 32 + m * 16 + ((lane >> 4) << 2) + j;
                if (gr < M) {
                    const float v = acc[m][n][j] + bv;
                    C[(size_t)gr * 128 + c] = v;
                    colsum[n] += v; colsq[n] += v * v;
                }
            }
        }
    }
    if (do_stats) {
        float* ssum = (float*)lsBhi;   // reuse tile LDS
        float* ssq  = ssum + 128;
        __syncthreads();
        if (tid < 128) { ssum[tid] = 0.f; ssq[tid] = 0.f; }
        __syncthreads();
        #pragma unroll
        for (int n = 0; n < 4; ++n) {
            const int c = wn * 64 + n * 16 + (lane & 15);
            atomicAdd(&ssum[c], colsum[n]);
            atomicAdd(&ssq[c], colsq[n]);
        }
        __syncthreads();
        if (tid < 128) {
            atomicAdd(&stats[tid],       ssum[tid]);
            atomicAdd(&stats[128 + tid], ssq[tid]);
        }
    }
}

// ------ weight transpose+split: W[nmat][K][128] -> Whi/Wlo[nmat][128][Kpad] ----
__global__ __launch_bounds__(256) void wt_cast2(const float* __restrict__ W,
                                                u16* __restrict__ Whi,
                                                u16* __restrict__ Wlo,
                                                int total, int K, int Kpad) {
    const int idx = blockIdx.x * 256 + threadIdx.x;
    if (idx >= total) return;
    const int perm = 128 * Kpad;
    const int m = idx / perm, rem = idx - m * perm;
    const int n = rem / Kpad, k = rem - n * Kpad;
    const float v = (k < K) ? W[(size_t)m * K * 128 + (size_t)k * 128 + n] : 0.f;
    u16 hi, lo;
    splitbf(v, hi, lo);
    Whi[idx] = hi; Wlo[idx] = lo;
}

// ---------------- fp32 tiled GEMM (LSTM gates only) ----------------------------
template <bool BT>
__global__ __launch_bounds__(256) void gemm_f32(
    const float* __restrict__ A, const float* __restrict__ B,
    const float* __restrict__ bias, float* __restrict__ C,
    int M, int K, int Nc)
{
    __shared__ float As[32][68];
    __shared__ float Bs[32][132];
    const int tid = threadIdx.x;
    const int tx = tid & 15, ty = tid >> 4;
    const int row0 = blockIdx.x * 64, col0 = blockIdx.y * 128;
    float acc[4][8] = {};
    for (int k0 = 0; k0 < K; k0 += 32) {
        {
            const int kk = tid & 31, rb = tid >> 5;
            #pragma unroll
            for (int i = 0; i < 8; ++i) {
                const int r = rb + i * 8, gr = row0 + r, gk = k0 + kk;
                As[kk][r] = (gr < M && gk < K) ? A[(size_t)gr * K + gk] : 0.f;
            }
        }
        if (!BT) {
            const int c = tid & 127, kb = tid >> 7;
            #pragma unroll
            for (int i = 0; i < 16; ++i) {
                const int kk = kb + i * 2, gk = k0 + kk;
                Bs[kk][c] = (gk < K) ? B[(size_t)gk * Nc + col0 + c] : 0.f;
            }
        } else {
            const int kk = tid & 31, cb = tid >> 5;
            #pragma unroll
            for (int i = 0; i < 16; ++i) {
                const int c = cb + i * 8, gk = k0 + kk;
                Bs[kk][c] = (gk < K) ? B[(size_t)(col0 + c) * K + gk] : 0.f;
            }
        }
        __syncthreads();
        #pragma unroll 8
        for (int kk = 0; kk < 32; ++kk) {
            const float4 av  = *(const float4*)&As[kk][ty * 4];
            const float4 bv0 = *(const float4*)&Bs[kk][tx * 8];
            const float4 bv1 = *(const float4*)&Bs[kk][tx * 8 + 4];
            const float a[4] = {av.x, av.y, av.z, av.w};
            const float b[8] = {bv0.x, bv0.y, bv0.z, bv0.w, bv1.x, bv1.y, bv1.z, bv1.w};
            #pragma unroll
            for (int i = 0; i < 4; ++i)
                #pragma unroll
                for (int j = 0; j < 8; ++j)
                    acc[i][j] = fmaf(a[i], b[j], acc[i][j]);
        }
        __syncthreads();
    }
    #pragma unroll
    for (int j = 0; j < 8; ++j) {
        const float bv = bias ? bias[col0 + tx * 8 + j] : 0.f;
        #pragma unroll
        for (int i = 0; i < 4; ++i) acc[i][j] += bv;
    }
    #pragma unroll
    for (int i = 0; i < 4; ++i) {
        const int gr = row0 + ty * 4 + i;
        if (gr < M) {
            *(float4*)&C[(size_t)gr * Nc + col0 + tx * 8] =
                make_float4(acc[i][0], acc[i][1], acc[i][2], acc[i][3]);
            *(float4*)&C[(size_t)gr * Nc + col0 + tx * 8 + 4] =
                make_float4(acc[i][4], acc[i][5], acc[i][6], acc[i][7]);
        }
    }
}

// ---------------- CSR build (counting sort by destination) ---------------------
__global__ __launch_bounds__(256) void count_deg(const int* __restrict__ dst,
                                                 int* __restrict__ deg) {
    const int e = blockIdx.x * 256 + threadIdx.x;
    if (e < EE) atomicAdd(&deg[dst[e]], 1);
}

__global__ __launch_bounds__(512) void scan1(const int* __restrict__ deg,
                                             int* __restrict__ scanned,
                                             int* __restrict__ bsum) {
    __shared__ int s[512];
    const int t = threadIdx.x;
    const int i = blockIdx.x * 512 + t;
    const int v = (i < NN) ? deg[i] : 0;
    s[t] = v; __syncthreads();
    for (int o = 1; o < 512; o <<= 1) {
        const int tv = (t >= o) ? s[t - o] : 0;
        __syncthreads();
        s[t] += tv;
        __syncthreads();
    }
    if (i < NN) scanned[i] = s[t];
    if (t == 511) bsum[blockIdx.x] = s[511];
}

__global__ __launch_bounds__(128) void scan2(int* __restrict__ bsum, int nb) {
    __shared__ int s[128];
    const int t = threadIdx.x;
    const int v = (t < nb) ? bsum[t] : 0;
    s[t] = v; __syncthreads();
    for (int o = 1; o < 128; o <<= 1) {
        const int tv = (t >= o) ? s[t - o] : 0;
        __syncthreads();
        s[t] += tv;
        __syncthreads();
    }
    if (t < nb) bsum[t] = s[t] - v;  // exclusive
}

__global__ __launch_bounds__(256) void scan3(const int* __restrict__ deg,
                                             const int* __restrict__ scanned,
                                             const int* __restrict__ bsum,
                                             int* __restrict__ rowptr,
                                             int* __restrict__ cursor) {
    const int i = blockIdx.x * 256 + threadIdx.x;
    if (i < NN) {
        const int v = bsum[i >> 9] + scanned[i] - deg[i];
        rowptr[i] = v; cursor[i] = v;
    }
    if (i == 0) rowptr[NN] = EE;
}

__global__ __launch_bounds__(256) void fill_csr(const int* __restrict__ src,
                                                const int* __restrict__ dst,
                                                int* __restrict__ cursor,
                                                int* __restrict__ csrc) {
    const int e = blockIdx.x * 256 + threadIdx.x;
    if (e < EE) {
        const int pos = atomicAdd(&cursor[dst[e]], 1);
        csrc[pos] = src[e];
    }
}

// ==== fused aggregate + combine + BN-stats =====================================
// z[dst] = (1+eps)*proj[dst] + sum_{src in N(dst)} proj[src] + b1, plus
// per-column sum/sumsq atomics. One wave per dst node (4 nodes per wave),
// float4 loads covering 2 source rows per instruction (lane<32 / lane>=32).
__global__ __launch_bounds__(256) void agg_combine(
    const float* __restrict__ proj, const int* __restrict__ rowptr,
    const int* __restrict__ csrc, const float* __restrict__ b1,
    const float* __restrict__ eps_arr, int eps_idx,
    float* __restrict__ z, float* __restrict__ stats)
{
    __shared__ float red[256];
    const int tid = threadIdx.x, lane = tid & 63, wave = tid >> 6;
    const float e1 = 1.f + eps_arr[eps_idx];
    const int half = lane >> 5;
    const int l32 = lane & 31;
    const float4* p4 = (const float4*)proj;
    float s[4] = {0.f, 0.f, 0.f, 0.f}, q[4] = {0.f, 0.f, 0.f, 0.f};
    float4 bv = make_float4(0.f, 0.f, 0.f, 0.f);
    if (lane < 32) bv = ((const float4*)b1)[l32];
    red[tid] = 0.f;
    __syncthreads();
    const int nbase = blockIdx.x * 16 + wave * 4;
    for (int t = 0; t < 4; ++t) {
        const int wid = nbase + t;
        const int s0 = rowptr[wid], s1 = rowptr[wid + 1];
        float ax = 0.f, ay = 0.f, az = 0.f, aw = 0.f;
        int j = s0;
        for (; j + 3 < s1; j += 4) {
            const int ra = csrc[j + half];
            const int rb = csrc[j + 2 + half];
            const float4 v0 = p4[(size_t)ra * 32 + l32];
            const float4 v1 = p4[(size_t)rb * 32 + l32];
            ax += v0.x + v1.x; ay += v0.y + v1.y;
            az += v0.z + v1.z; aw += v0.w + v1.w;
        }
        for (; j + 1 < s1; j += 2) {
            const int ra = csrc[j + half];
            const float4 v0 = p4[(size_t)ra * 32 + l32];
            ax += v0.x; ay += v0.y; az += v0.z; aw += v0.w;
        }
        if (j < s1 && half == 0) {
            const float4 v0 = p4[(size_t)csrc[j] * 32 + l32];
            ax += v0.x; ay += v0.y; az += v0.z; aw += v0.w;
        }
        ax += __shfl_down(ax, 32, 64);
        ay += __shfl_down(ay, 32, 64);
        az += __shfl_down(az, 32, 64);
        aw += __shfl_down(aw, 32, 64);
        if (lane < 32) {
            const float4 self = p4[(size_t)wid * 32 + l32];
            float4 zv;
            zv.x = fmaf(e1, self.x, ax + bv.x);
            zv.y = fmaf(e1, self.y, ay + bv.y);
            zv.z = fmaf(e1, self.z, az + bv.z);
            zv.w = fmaf(e1, self.w, aw + bv.w);
            ((float4*)z)[(size_t)wid * 32 + l32] = zv;
            s[0] += zv.x; s[1] += zv.y; s[2] += zv.z; s[3] += zv.w;
            q[0] += zv.x * zv.x; q[1] += zv.y * zv.y;
            q[2] += zv.z * zv.z; q[3] += zv.w * zv.w;
        }
    }
    if (lane < 32) {
        const int d = l32 * 4;
        #pragma unroll
        for (int c = 0; c < 4; ++c) {
            atomicAdd(&red[d + c], s[c]);
            atomicAdd(&red[128 + d + c], q[c]);
        }
    }
    __syncthreads();
    atomicAdd(&stats[tid], red[tid]);
}

// ------- BN + ReLU -> fp32 (final h only) --------------------------------------
__global__ __launch_bounds__(256) void bn_relu_f32(
    const float* __restrict__ xin, const float* __restrict__ stats,
    const float* __restrict__ gamma, const float* __restrict__ beta,
    float* __restrict__ out)
{
    const size_t i = (size_t)blockIdx.x * 256 + threadIdx.x;  // pair index
    if (i >= (size_t)NN * 64) return;
    const int d = (int)(i & 63) * 2;
    const float inv_n = 1.f / NN;
    const float mu0 = stats[d] * inv_n,     mu1 = stats[d + 1] * inv_n;
    const float v0 = fmaxf(stats[128 + d] * inv_n - mu0 * mu0, 0.f);
    const float v1 = fmaxf(stats[129 + d] * inv_n - mu1 * mu1, 0.f);
    const float s0 = gamma[d] * rsqrtf(v0 + 1e-5f);
    const float s1 = gamma[d + 1] * rsqrtf(v1 + 1e-5f);
    const float2 xv = ((const float2*)xin)[i];
    const float y0 = fmaxf(fmaf(s0, xv.x - mu0, beta[d]), 0.f);
    const float y1 = fmaxf(fmaf(s1, xv.y - mu1, beta[d + 1]), 0.f);
    ((float2*)out)[i] = make_float2(y0, y1);
}

// ---------------- per-graph segment starts (batch is sorted) -------------------
__global__ __launch_bounds__(256) void seg_starts(const int* __restrict__ batch,
                                                  int* __restrict__ gstart) {
    const int i = blockIdx.x * 256 + threadIdx.x;
    if (i >= NN) return;
    const int b = batch[i];
    if (i == 0) { for (int g = 0; g <= b; ++g) gstart[g] = 0; }
    else {
        const int pb = batch[i - 1];
        for (int g = pb + 1; g <= b; ++g) gstart[g] = i;
    }
    if (i == NN - 1) { for (int g = b + 1; g <= GG; ++g) gstart[g] = NN; }
}

// ---------------- Set2Set ------------------------------------------------------
__global__ __launch_bounds__(256) void pack_wcat(const float* __restrict__ Wih,
                                                 const float* __restrict__ Whh,
                                                 float* __restrict__ Wcat) {
    const int i = blockIdx.x * 256 + threadIdx.x;
    if (i >= 512 * 384) return;
    const int j = i / 384, k = i - j * 384;
    Wcat[i] = (k < 256) ? Wih[j * 256 + k] : Whh[j * 128 + (k - 256)];
}

__global__ __launch_bounds__(256) void lstm_kernel(
    const float* __restrict__ gates, const float* __restrict__ bih,
    const float* __restrict__ bhh, float* __restrict__ cc, float* __restrict__ S)
{
    const int i = blockIdx.x * 256 + threadIdx.x;
    if (i >= GG * 128) return;
    const int g = i >> 7, d = i & 127;
    const float* gr = gates + (size_t)g * 512;
    const float ig = gr[d]       + bih[d]       + bhh[d];
    const float fg = gr[128 + d] + bih[128 + d] + bhh[128 + d];
    const float gv = gr[256 + d] + bih[256 + d] + bhh[256 + d];
    const float og = gr[384 + d] + bih[384 + d] + bhh[384 + d];
    const float c  = sigmf(fg) * cc[i] + sigmf(ig) * tanhf(gv);
    const float hv = sigmf(og) * tanhf(c);
    cc[i] = c;
    S[(size_t)g * 384 + d] = hv;
    S[(size_t)g * 384 + 256 + d] = hv;
}

__global__ __launch_bounds__(256) void attend_kernel(
    const float* __restrict__ h, float* __restrict__ S,
    float* __restrict__ ews, const int* __restrict__ gstart)
{
    const int g = blockIdx.x;
    const int rs = gstart[g], re = gstart[g + 1];
    const int tid = threadIdx.x, lane = tid & 63, w = tid >> 6;
    __shared__ float q[128];
    __shared__ float red[8];
    if (tid < 128) q[tid] = S[(size_t)g * 384 + 256 + tid];
    __syncthreads();
    const float2* h2 = (const float2*)h;
    float lmax = -1e30f;
    for (int n = rs + w; n < re; n += 4) {
        const float2 hv = h2[(size_t)n * 64 + lane];
        float p = hv.x * q[2 * lane] + hv.y * q[2 * lane + 1];
        #pragma unroll
        for (int o = 32; o; o >>= 1) p += __shfl_down(p, o, 64);
        if (lane == 0) { ews[n] = p; lmax = fmaxf(lmax, p); }
    }
    if (lane == 0) red[w] = lmax;
    __syncthreads();
    const float m = fmaxf(fmaxf(red[0], red[1]), fmaxf(red[2], red[3]));
    __syncthreads();
    float lsum = 0.f;
    for (int n = rs + tid; n < re; n += 256) {
        const float ex = expf(ews[n] - m);
        ews[n] = ex; lsum += ex;
    }
    #pragma unroll
    for (int o = 32; o; o >>= 1) lsum += __shfl_down(lsum, o, 64);
    if (lane == 0) red[w] = lsum;
    __syncthreads();
    const float denom = red[0] + red[1] + red[2] + red[3];
    if (tid < 128) {
        float acc = 0.f;
        for (int n = rs; n < re; ++n)
            acc = fmaf(ews[n], h[(size_t)n * 128 + tid], acc);
        S[(size_t)g * 384 + 128 + tid] = (denom > 0.f) ? acc / denom : 0.f;
    }
}

__global__ __launch_bounds__(128) void fc1_kernel(const float* __restrict__ S,
                                                  const float* __restrict__ W,
                                                  const float* __restrict__ b,
                                                  float* __restrict__ out1) {
    const int g = blockIdx.x, d = threadIdx.x;
    __shared__ float qs[256];
    qs[d] = S[(size_t)g * 384 + d];
    qs[128 + d] = S[(size_t)g * 384 + 128 + d];
    __syncthreads();
    float acc = b[d];
    for (int k = 0; k < 256; ++k) acc = fmaf(qs[k], W[k * 128 + d], acc);
    out1[(size_t)g * 128 + d] = fmaxf(acc, 0.f);
}

__global__ __launch_bounds__(256) void fc4_kernel(const float* __restrict__ out1,
                                                  const float* __restrict__ W,
                                                  const float* __restrict__ b,
                                                  float* __restrict__ out) {
    const int i = blockIdx.x * 256 + threadIdx.x;
    if (i >= GG * 12) return;
    const int g = i / 12, j = i - g * 12;
    float acc = b[j];
    for (int d = 0; d < 128; ++d)
        acc = fmaf(out1[(size_t)g * 128 + d], W[d * 12 + j], acc);
    out[i] = acc;
}

// ================================================================================
extern "C" void kernel_launch(void* const* d_in, const int* in_sizes, int n_in,
                              void* d_out, int out_size, void* d_ws, size_t ws_size,
                              hipStream_t stream)
{
    const float* x        = (const float*)d_in[0];
    const int*   eidx[3]  = {(const int*)d_in[1], (const int*)d_in[2], (const int*)d_in[3]};
    const int*   batch    = (const int*)d_in[4];
    const float* conv1_W1     = (const float*)d_in[5];
    const float* conv1_b1     = (const float*)d_in[6];
    const float* conv_rest_W1 = (const float*)d_in[7];
    const float* conv_rest_b1 = (const float*)d_in[8];
    const float* conv_W2      = (const float*)d_in[9];
    const float* conv_b2      = (const float*)d_in[10];
    const float* conv_bn1_g   = (const float*)d_in[11];
    const float* conv_bn1_b   = (const float*)d_in[12];
    const float* conv_bn2_g   = (const float*)d_in[13];
    const float* conv_bn2_b   = (const float*)d_in[14];
    const float* conv_eps     = (const float*)d_in[15];
    const float* mlp_W1       = (const float*)d_in[16];
    const float* mlp_b1       = (const float*)d_in[17];
    const float* mlp_bn1_g    = (const float*)d_in[18];
    const float* mlp_bn1_b    = (const float*)d_in[19];
    const float* mlp_W2       = (const float*)d_in[20];
    const float* mlp_b2       = (const float*)d_in[21];
    const float* mlp_bn2_g    = (const float*)d_in[22];
    const float* mlp_bn2_b    = (const float*)d_in[23];
    const float* lstm_Wih     = (const float*)d_in[24];
    const float* lstm_Whh     = (const float*)d_in[25];
    const float* lstm_bih     = (const float*)d_in[26];
    const float* lstm_bhh     = (const float*)d_in[27];
    const float* fc1_W        = (const float*)d_in[28];
    const float* fc1_b        = (const float*)d_in[29];
    const float* fc4_W        = (const float*)d_in[30];
    const float* fc4_b        = (const float*)d_in[31];
    float* outp = (float*)d_out;

    // ---- workspace layout ----
    float* f = (float*)d_ws;
    size_t fo = 0;
    float* proj  = f + fo; fo += (size_t)NN * 128;  // also fusion-MLP out (zm1)
    float* z1    = f + fo; fo += (size_t)NN * 128;  // conv z; also final h
    float* z2a   = f + fo; fo += (size_t)NN * 128;
    float* z2b   = f + fo; fo += (size_t)NN * 128;
    float* z2c   = f + fo; fo += (size_t)NN * 128;
    float* zm2   = f + fo; fo += (size_t)NN * 128;
    float* ews   = f + fo; fo += NN;
    float* stats = f + fo; fo += 48 * 256;
    float* S     = f + fo; fo += (size_t)GG * 384;
    float* ccb   = f + fo; fo += (size_t)GG * 128;
    float* gates = f + fo; fo += (size_t)GG * 512;  // reused as fc1 output
    float* Wcat  = f + fo; fo += (size_t)512 * 384;
    float* zm1 = proj;
    float* hbuf = z1;
    fo = (fo + 7) & ~(size_t)7;   // 16B-align bf16 region
    u16* b = (u16*)(f + fo);
    size_t bo = 0;
    u16* c1_hi   = b + bo; bo += (size_t)3 * 128 * 1280;
    u16* c1_lo   = b + bo; bo += (size_t)3 * 128 * 1280;
    u16* rw1_hi  = b + bo; bo += (size_t)15 * 128 * 128;
    u16* rw1_lo  = b + bo; bo += (size_t)15 * 128 * 128;
    u16* w2_hi   = b + bo; bo += (size_t)18 * 128 * 128;
    u16* w2_lo   = b + bo; bo += (size_t)18 * 128 * 128;
    u16* mw1_hi  = b + bo; bo += (size_t)6 * 128 * 384;
    u16* mw1_lo  = b + bo; bo += (size_t)6 * 128 * 384;
    u16* mw2_hi  = b + bo; bo += (size_t)6 * 128 * 128;
    u16* mw2_lo  = b + bo; bo += (size_t)6 * 128 * 128;
    int* ip = (int*)(b + bo);
    size_t io = 0;
    int* rowptr[3]; int* csrc[3];
    for (int s = 0; s < 3; ++s) { rowptr[s] = ip + io; io += NN + 1; }
    for (int s = 0; s < 3; ++s) { csrc[s]   = ip + io; io += EE; }
    int* deg     = ip + io; io += NN;
    int* cursor  = ip + io; io += NN;
    int* scanned = ip + io; io += NN;
    int* bsum    = ip + io; io += 128;
    int* gstart  = ip + io; io += GG + 1;
    const size_t need = fo * 4 + bo * 2 + io * 4;
    if (ws_size < need) return;

    const int NBLK_SCAN = (NN + 511) / 512;

    // ---- weight transpose+split (K padded to x64) ----
    {
        int t;
        t = 3 * 128 * 1280;
        wt_cast2<<<(t + 255) / 256, 256, 0, stream>>>(conv1_W1, c1_hi, c1_lo, t, FIN, 1280);
        t = 15 * 128 * 128;
        wt_cast2<<<(t + 255) / 256, 256, 0, stream>>>(conv_rest_W1, rw1_hi, rw1_lo, t, 128, 128);
        t = 18 * 128 * 128;
        wt_cast2<<<(t + 255) / 256, 256, 0, stream>>>(conv_W2, w2_hi, w2_lo, t, 128, 128);
        t = 6 * 128 * 384;
        wt_cast2<<<(t + 255) / 256, 256, 0, stream>>>(mlp_W1, mw1_hi, mw1_lo, t, 384, 384);
        t = 6 * 128 * 128;
        wt_cast2<<<(t + 255) / 256, 256, 0, stream>>>(mlp_W2, mw2_hi, mw2_lo, t, 128, 128);
    }

    // ---- CSR build for the 3 edge sets ----
    for (int s = 0; s < 3; ++s) {
        hipMemsetAsync(deg, 0, NN * sizeof(int), stream);
        count_deg<<<(EE + 255) / 256, 256, 0, stream>>>(eidx[s] + EE, deg);
        scan1<<<NBLK_SCAN, 512, 0, stream>>>(deg, scanned, bsum);
        scan2<<<1, 128, 0, stream>>>(bsum, NBLK_SCAN);
        scan3<<<(NN + 255) / 256, 256, 0, stream>>>(deg, scanned, bsum, rowptr[s], cursor);
        fill_csr<<<(EE + 255) / 256, 256, 0, stream>>>(eidx[s], eidx[s] + EE, cursor, csrc[s]);
    }
    seg_starts<<<(NN + 255) / 256, 256, 0, stream>>>(batch, gstart);
    hipMemsetAsync(stats, 0, 48 * 256 * sizeof(float), stream);
    hipMemsetAsync(S, 0, (size_t)GG * 384 * sizeof(float), stream);
    hipMemsetAsync(ccb, 0, (size_t)GG * 128 * sizeof(float), stream);

    const int GG64 = (NN + 63) / 64;     // 782 blocks
    const int AGG_GRID = NN / 16;        // 3125 blocks
    float* z2[3] = {z2a, z2b, z2c};

    // ---- 6 GIN layers ----
    for (int l = 0; l < 6; ++l) {
        float* slotF1 = stats + (size_t)(l * 8 + 6) * 256;
        float* slotF2 = stats + (size_t)(l * 8 + 7) * 256;
        for (int k = 0; k < 3; ++k) {
            const int lk = l * 3 + k;
            const float* b1 = (l == 0) ? conv1_b1 + k * 128
                                       : conv_rest_b1 + ((l - 1) * 3 + k) * 128;
            float* slot0 = stats + (size_t)(l * 8 + k * 2) * 256;
            float* slot1 = stats + (size_t)(l * 8 + k * 2 + 1) * 256;

            if (l == 0)
                gemm_bn<0><<<GG64, 256, 0, stream>>>(
                    x, nullptr, nullptr, FIN, 1280, FIN,
                    nullptr, nullptr, nullptr, nullptr, nullptr, nullptr,
                    nullptr, nullptr, nullptr,
                    c1_hi + (size_t)k * 128 * 1280, c1_lo + (size_t)k * 128 * 1280,
                    nullptr, proj, NN, 0, nullptr);
            else
                gemm_bn<1><<<GG64, 256, 0, stream>>>(
                    zm2, nullptr, nullptr, 128, 128, 128,
                    stats + (size_t)((l - 1) * 8 + 7) * 256, nullptr, nullptr,
                    mlp_bn2_g + (l - 1) * 128, nullptr, nullptr,
                    mlp_bn2_b + (l - 1) * 128, nullptr, nullptr,
                    rw1_hi + (size_t)((l - 1) * 3 + k) * 128 * 128,
                    rw1_lo + (size_t)((l - 1) * 3 + k) * 128 * 128,
                    nullptr, proj, NN, 0, nullptr);

            agg_combine<<<AGG_GRID, 256, 0, stream>>>(
                proj, rowptr[k], csrc[k], b1, conv_eps, lk, z1, slot0);

            gemm_bn<1><<<GG64, 256, 0, stream>>>(
                z1, nullptr, nullptr, 128, 128, 128,
                slot0, nullptr, nullptr,
                conv_bn1_g + lk * 128, nullptr, nullptr,
                conv_bn1_b + lk * 128, nullptr, nullptr,
                w2_hi + (size_t)lk * 128 * 128, w2_lo + (size_t)lk * 128 * 128,
                conv_b2 + lk * 128, z2[k], NN, 1, slot1);
        }
        // fusion MLP layer 1: concat(bn_relu(z2_0..2)) @ W1
        gemm_bn<2><<<GG64, 256, 0, stream>>>(
            z2a, z2b, z2c, 128, 384, 384,
            stats + (size_t)(l * 8 + 1) * 256,
            stats + (size_t)(l * 8 + 3) * 256,
            stats + (size_t)(l * 8 + 5) * 256,
            conv_bn2_g + (l * 3 + 0) * 128, conv_bn2_g + (l * 3 + 1) * 128,
            conv_bn2_g + (l * 3 + 2) * 128,
            conv_bn2_b + (l * 3 + 0) * 128, conv_bn2_b + (l * 3 + 1) * 128,
            conv_bn2_b + (l * 3 + 2) * 128,
            mw1_hi + (size_t)l * 128 * 384, mw1_lo + (size_t)l * 128 * 384,
            mlp_b1 + l * 128, zm1, NN, 1, slotF1);
        // fusion MLP layer 2
        gemm_bn<1><<<GG64, 256, 0, stream>>>(
            zm1, nullptr, nullptr, 128, 128, 128,
            slotF1, nullptr, nullptr,
            mlp_bn1_g + l * 128, nullptr, nullptr,
            mlp_bn1_b + l * 128, nullptr, nullptr,
            mw2_hi + (size_t)l * 128 * 128, mw2_lo + (size_t)l * 128 * 128,
            mlp_b2 + l * 128, zm2, NN, 1, slotF2);
    }
    // final h = bn_relu(zm2, layer-5 stats)
    bn_relu_f32<<<(NN * 64 + 255) / 256, 256, 0, stream>>>(
        zm2, stats + (size_t)(5 * 8 + 7) * 256,
        mlp_bn2_g + 5 * 128, mlp_bn2_b + 5 * 128, hbuf);

    // ---- Set2Set readout (fp32) ----
    pack_wcat<<<(512 * 384 + 255) / 256, 256, 0, stream>>>(lstm_Wih, lstm_Whh, Wcat);
    for (int t = 0; t < 6; ++t) {
        gemm_f32<true><<<dim3(8, 4), 256, 0, stream>>>(
            S, Wcat, nullptr, gates, GG, 384, 512);
        lstm_kernel<<<(GG * 128 + 255) / 256, 256, 0, stream>>>(
            gates, lstm_bih, lstm_bhh, ccb, S);
        attend_kernel<<<GG, 256, 0, stream>>>(hbuf, S, ews, gstart);
    }
    fc1_kernel<<<GG, 128, 0, stream>>>(S, fc1_W, fc1_b, gates);
    fc4_kernel<<<(GG * 12 + 255) / 256, 256, 0, stream>>>(gates, fc4_W, fc4_b, outp);
}